// Round 11
// baseline (55.457 us; speedup 1.0000x reference)
//
#include <hip/hip_runtime.h>
#include <hip/hip_bf16.h>
#include <stdint.h>

#define B_ 4
#define N_ 2000
#define T_ 12
#define D_ 64
#define K_ 3
#define DEG_ 8
#define E_ (N_*DEG_)              // 16000
#define ROWS_ (B_*N_*T_)          // 96000
#define NT_ (N_*T_)               // 24000
#define EPN_ (B_*T_*D_)           // 3072 elements per node row
#define V4PB_ (T_*D_/4)           // 192 vec4 per (node,b)
#define ROWBYTES_ (EPN_*4)        // 12288 bytes per node row
#define LOG2E_ 1.4426950408889634f

typedef __attribute__((ext_vector_type(8))) short short8v;   // 8 bf16 = 4 VGPR
typedef __attribute__((ext_vector_type(4))) float f32x4;     // MFMA acc

__device__ __forceinline__ uint32_t f32_to_bf16_bits(float x) {
    uint32_t u = __float_as_uint(x);
    return (u + 0x7FFFu + ((u >> 16) & 1u)) >> 16;   // RNE
}
__device__ __forceinline__ uint32_t pack2(float p, float f) {
    return (f32_to_bf16_bits(p) << 16) | f32_to_bf16_bits(f);
}

// ---------- Kernel 0 (prep): WB[c][k] = bf16( c<64 ? Wm[k][c] : log2e*(Wm@W1)[k][c-64] )
//            bpp[d] = log2e * (b_mlp @ W1)[d]        (W1 = W_attn[:64])
// W2/b_attn cancel inside the per-dst softmax; the max-shift also cancels, so
// the logit half is pre-exponentiated downstream. WB is the MFMA W-operand
// (transposed, k-contiguous), in the head of d_out (gcn fully overwrites out).
__global__ void prep_kernel(const float* __restrict__ Wm,
                            const float* __restrict__ Wa,
                            const float* __restrict__ bm,
                            uint16_t* __restrict__ WB,
                            float* __restrict__ bpp) {
    const int tk = threadIdx.x;          // k (or d for bias block)
    const int c  = blockIdx.x;           // 0..128
    if (c < 64) {
        WB[c*64 + tk] = (uint16_t)f32_to_bf16_bits(Wm[tk*64 + c]);
    } else if (c < 128) {
        const int cp = c - 64;
        float s = 0.f;
        #pragma unroll
        for (int e = 0; e < 64; ++e) s += Wm[tk*64 + e] * Wa[e*64 + cp];
        WB[c*64 + tk] = (uint16_t)f32_to_bf16_bits(s * LOG2E_);
    } else {
        float s = 0.f;
        #pragma unroll
        for (int e = 0; e < 64; ++e) s += bm[e] * Wa[e*64 + tk];
        bpp[tk] = s * LOG2E_;
    }
}

// ---------- Kernel 1: MFMA GEMM [96000x64]@[64x128] -> pack (exp2(logit), feat) ----------
// R7 tiling (64 rows/block, 4 waves, 8 col-tiles x 2 K-steps) with SWAPPED MFMA
// operands: acc = mfma(wfrag, xfrag). Validated output map (lane&15 <-> 2nd
// operand index, q*4+reg <-> 1st operand index) then gives each lane ONE X-row
// (row0+r) x 4 consecutive W-cols (tile*16+q*4+reg) -> d-contiguous uint4
// stores (4/thread, full 64B lines) and a single (b,n,tt) index chain per lane.
__launch_bounds__(256)
__global__ void mlp_mfma(const float* __restrict__ X,
                         const uint16_t* __restrict__ WB,
                         const float* __restrict__ bm,
                         const float* __restrict__ bpp,
                         uint32_t* __restrict__ packed) {
    const int t    = threadIdx.x;
    const int wave = t >> 6, lane = t & 63;
    const int r    = lane & 15, q = lane >> 4;

    // W fragments: lane holds WB[c=tile*16+r][k=s*32+q*8 .. +7] (k-contiguous)
    short8v wfrag[8][2];
    #pragma unroll
    for (int tile = 0; tile < 8; ++tile) {
        const int c = tile*16 + r;
        #pragma unroll
        for (int s = 0; s < 2; ++s)
            wfrag[tile][s] = *(const short8v*)(WB + c*64 + s*32 + q*8);
    }

    const int row0 = blockIdx.x*64 + wave*16;
    const int gR   = row0 + r;            // this lane's X-row
    const int b    = gR / NT_;            // -> (b,n,tt), once per lane
    const int rm   = gR - b*NT_;
    const int n    = rm / T_;
    const int tt   = rm - n*T_;
    uint32_t* dstrow = packed + (size_t)n*EPN_ + b*(T_*D_) + tt*D_;

    f32x4 acc[8];
    #pragma unroll
    for (int tile = 0; tile < 8; ++tile) acc[tile] = (f32x4){0.f,0.f,0.f,0.f};

    #pragma unroll
    for (int s = 0; s < 2; ++s) {
        const float* xp = X + (size_t)gR*64 + s*32 + q*8;
        const float4 x0 = *(const float4*)xp;
        const float4 x1 = *(const float4*)(xp + 4);
        short8v af;
        af[0] = (short)f32_to_bf16_bits(x0.x);
        af[1] = (short)f32_to_bf16_bits(x0.y);
        af[2] = (short)f32_to_bf16_bits(x0.z);
        af[3] = (short)f32_to_bf16_bits(x0.w);
        af[4] = (short)f32_to_bf16_bits(x1.x);
        af[5] = (short)f32_to_bf16_bits(x1.y);
        af[6] = (short)f32_to_bf16_bits(x1.z);
        af[7] = (short)f32_to_bf16_bits(x1.w);
        #pragma unroll
        for (int tile = 0; tile < 8; ++tile)
            acc[tile] = __builtin_amdgcn_mfma_f32_16x16x32_bf16(
                            wfrag[tile][s], af, acc[tile], 0, 0, 0);
    }

    // Epilogue: lane owns X-row gR, W-cols tile*16 + q*4 + reg.
    // Tile pair (tf, tf+4) = (feats cols, matching logit cols).
    #pragma unroll
    for (int tf = 0; tf < 4; ++tf) {
        const int d0 = tf*16 + q*4;
        const float4 bm4 = *(const float4*)&bm[d0];
        const float4 bp4 = *(const float4*)&bpp[d0];
        uint4 u;
        u.x = pack2(__builtin_amdgcn_exp2f(acc[tf+4][0] + bp4.x), acc[tf][0] + bm4.x);
        u.y = pack2(__builtin_amdgcn_exp2f(acc[tf+4][1] + bp4.y), acc[tf][1] + bm4.y);
        u.z = pack2(__builtin_amdgcn_exp2f(acc[tf+4][2] + bp4.z), acc[tf][2] + bm4.z);
        u.w = pack2(__builtin_amdgcn_exp2f(acc[tf+4][3] + bp4.w), acc[tf][3] + bm4.w);
        *(uint4*)(dstrow + d0) = u;
    }
}

// ---------- Kernel 2: per-node 8-edge softmax aggregation, K graphs ----------
// 1D grid of 12000 blocks (2 waves = 2 nodes each), XCD-phase partitioned
// (xcd = wgid%8 round-robin -> each XCD owns a contiguous 1.5-phase span, its
// L2 holds 1-2 packed byte-stripes for the whole kernel; validated R10: -11 µs).
__launch_bounds__(128, 4)
__global__ void gcn_kernel(const uint32_t* __restrict__ packed,
                           const float* __restrict__ input,
                           const int* __restrict__ edges,
                           const float* __restrict__ weight,
                           float* __restrict__ out) {
    const uint32_t wgid = blockIdx.x;          // [0,12000)
    const uint32_t xcd  = wgid & 7;            // assumed XCD id (round-robin)
    const uint32_t slot = wgid >> 3;           // [0,1500) within XCD
    const uint32_t vw   = xcd * 1500u + slot;  // phase-major virtual work item
    const int ss   = (int)(vw / 1000u);        // phase [0,12)
    const int pair = (int)(vw - (uint32_t)ss * 1000u);   // [0,1000)

    const int wv = __builtin_amdgcn_readfirstlane(threadIdx.x >> 6);  // wave 0/1
    const int n  = pair*2 + wv;
    const int t  = threadIdx.x & 63;      // lane

    const int vv = ss*64 + t;             // uint4 index within node row [0,768)
    const int b  = vv / V4PB_;
    const int r4 = vv - b*V4PB_;
    const size_t off4 = (size_t)b*(NT_*D_/4) + (size_t)n*V4PB_ + r4;
    const float4 inv = ((const float4*)input)[off4];   // residual, issued early

    // Wave-uniform edge indices (SGPR) for all 3 graphs.
    int srcs[24];
    #pragma unroll
    for (int k = 0; k < K_; ++k) {
        const int4 e0 = *(const int4*)(edges + (size_t)k*(2*E_) + n*DEG_);
        const int4 e1 = *(const int4*)(edges + (size_t)k*(2*E_) + n*DEG_ + 4);
        srcs[k*8+0]=e0.x; srcs[k*8+1]=e0.y; srcs[k*8+2]=e0.z; srcs[k*8+3]=e0.w;
        srcs[k*8+4]=e1.x; srcs[k*8+5]=e1.y; srcs[k*8+6]=e1.z; srcs[k*8+7]=e1.w;
    }

    uint4 pu[24];
    #pragma unroll
    for (int idx = 0; idx < 24; ++idx) {
        const char* base = (const char*)packed
                         + (size_t)((uint32_t)srcs[idx] * (uint32_t)ROWBYTES_);
        pu[idx] = *(const uint4*)(base + (size_t)vv * 16);
    }

    float acc[4] = {0.f, 0.f, 0.f, 0.f};
    #pragma unroll
    for (int k = 0; k < K_; ++k) {
        const float wk = weight[k];
        const uint32_t* pw = (const uint32_t*)&pu[k*8];
        #pragma unroll
        for (int qq = 0; qq < 4; ++qq) {
            float s = 0.f, num = 0.f;
            #pragma unroll
            for (int j = 0; j < 8; ++j) {
                const uint32_t u = pw[j*4 + qq];
                const float p = __uint_as_float(u & 0xFFFF0000u);  // exp(logit), bf16
                const float f = __uint_as_float(u << 16);          // feats, bf16
                s += p;
                num = fmaf(p, f, num);
            }
            acc[qq] += wk * num * __builtin_amdgcn_rcpf(s);
        }
    }

    float4 o;
    o.x = (acc[0] > 0.f ? acc[0] : 0.01f*acc[0]) + inv.x;
    o.y = (acc[1] > 0.f ? acc[1] : 0.01f*acc[1]) + inv.y;
    o.z = (acc[2] > 0.f ? acc[2] : 0.01f*acc[2]) + inv.z;
    o.w = (acc[3] > 0.f ? acc[3] : 0.01f*acc[3]) + inv.w;
    ((float4*)out)[off4] = o;
}

extern "C" void kernel_launch(void* const* d_in, const int* in_sizes, int n_in,
                              void* d_out, int out_size, void* d_ws, size_t ws_size,
                              hipStream_t stream) {
    const float* input  = (const float*)d_in[0];
    const float* Wm     = (const float*)d_in[1];
    const float* bm     = (const float*)d_in[2];
    const float* Wa     = (const float*)d_in[3];
    // d_in[4] = b_attn (cancels inside per-dst softmax), unused
    const float* weight = (const float*)d_in[5];
    const int*   edges  = (const int*)d_in[6];
    float* out = (float*)d_out;
    uint32_t* packed = (uint32_t*)d_ws;   // [N][B][T][D] of (bf16 exp(logit) | bf16 feats)

    // Prep scratch lives in the head of d_out; gcn_kernel fully overwrites out.
    uint16_t* WB  = (uint16_t*)d_out;             // 128 cols x 64 k bf16 = 16 KB
    float*    bpp = (float*)d_out + 4096;         // 64 floats

    hipLaunchKernelGGL(prep_kernel, dim3(129), dim3(64), 0, stream, Wm, Wa, bm, WB, bpp);
    hipLaunchKernelGGL(mlp_mfma, dim3(ROWS_/64), dim3(256), 0, stream,
                       input, WB, bm, bpp, packed);
    hipLaunchKernelGGL(gcn_kernel, dim3(12000), dim3(128), 0, stream,
                       packed, input, edges, weight, out);
}

// Round 12
// 51.103 us; speedup vs baseline: 1.0852x; 1.0852x over previous
//
#include <hip/hip_runtime.h>
#include <hip/hip_bf16.h>
#include <stdint.h>

#define B_ 4
#define N_ 2000
#define T_ 12
#define D_ 64
#define K_ 3
#define DEG_ 8
#define E_ (N_*DEG_)              // 16000
#define ROWS_ (B_*N_*T_)          // 96000
#define NT_ (N_*T_)               // 24000
#define EPN_ (B_*T_*D_)           // 3072 elements per node row
#define V4PB_ (T_*D_/4)           // 192 vec4 per (node,b)
#define ROWBYTES_ (EPN_*4)        // 12288 bytes per node row
#define LOG2E_ 1.4426950408889634f

typedef __attribute__((ext_vector_type(8))) short short8v;   // 8 bf16 = 4 VGPR
typedef __attribute__((ext_vector_type(4))) float f32x4;     // MFMA acc

__device__ __forceinline__ uint32_t f32_to_bf16_bits(float x) {
    uint32_t u = __float_as_uint(x);
    return (u + 0x7FFFu + ((u >> 16) & 1u)) >> 16;   // RNE
}
__device__ __forceinline__ uint32_t pack2(float p, float f) {
    return (f32_to_bf16_bits(p) << 16) | f32_to_bf16_bits(f);
}

// ---------- Kernel 0 (prep): fragment-linear W table + bias ----------
// WBf[(tile*2+s)*64 + lane][e] = bf16 of W-col c = tile*16 + (lane&15),
// k = s*32 + (lane>>4)*8 + e, where W-col c<64 is Wm[:,c] and c>=64 is
// log2e*(Wm@W1)[:,c-64]  (W1 = W_attn[:64]; W2/b_attn cancel in the per-dst
// softmax, and the max-shift cancels so the logit half is pre-exponentiated
// downstream). Fragment-linear order makes every mlp W-load a contiguous
// 1-KB wave load (was 16 x 64B segments -> 16 L1 transactions each).
__global__ void prep_kernel(const float* __restrict__ Wm,
                            const float* __restrict__ Wa,
                            const float* __restrict__ bm,
                            uint16_t* __restrict__ WBf,
                            float* __restrict__ bpp) {
    const int blk  = blockIdx.x;          // 0..16
    const int lane = threadIdx.x;         // 64
    if (blk < 16) {
        const int tile = blk >> 1, s = blk & 1;
        const int r = lane & 15, q = lane >> 4;
        const int c = tile*16 + r;
        uint16_t o[8];
        #pragma unroll
        for (int e = 0; e < 8; ++e) {
            const int k = s*32 + q*8 + e;
            float v;
            if (c < 64) {
                v = Wm[k*64 + c];
            } else {
                v = 0.f;
                #pragma unroll
                for (int j = 0; j < 64; ++j) v += Wm[k*64 + j] * Wa[j*64 + (c - 64)];
                v *= LOG2E_;
            }
            o[e] = (uint16_t)f32_to_bf16_bits(v);
        }
        *(uint4*)(WBf + (size_t)(blk*64 + lane)*8) = *(const uint4*)o;
    } else {
        float s = 0.f;
        #pragma unroll
        for (int e = 0; e < 64; ++e) s += bm[e] * Wa[e*64 + lane];
        bpp[lane] = s * LOG2E_;
    }
}

// ---------- Kernel 1: MFMA GEMM [96000x64]@[64x128] -> pack (exp2(logit), feat) ----------
// R11 tiling (64 rows/block, 4 waves, swapped operands: acc = mfma(wfrag, xfrag)
// -> lane owns one X-row x 4 consecutive W-cols, d-contiguous uint4 stores).
// W fragments now load from the fragment-linear WBf table: 16 contiguous 1-KB
// wave loads (L1-resident, identical for all 4 waves). No LDS, no barriers.
__launch_bounds__(256)
__global__ void mlp_mfma(const float* __restrict__ X,
                         const uint16_t* __restrict__ WBf,
                         const float* __restrict__ bm,
                         const float* __restrict__ bpp,
                         uint32_t* __restrict__ packed) {
    const int t    = threadIdx.x;
    const int wave = t >> 6, lane = t & 63;
    const int r    = lane & 15, q = lane >> 4;

    // W fragments, fragment-linear: slot (tile*2+s), 16 B per lane, contiguous.
    short8v wfrag[8][2];
    #pragma unroll
    for (int tile = 0; tile < 8; ++tile)
        #pragma unroll
        for (int s = 0; s < 2; ++s)
            wfrag[tile][s] = *(const short8v*)(WBf + (size_t)((tile*2+s)*64 + lane)*8);

    const int row0 = blockIdx.x*64 + wave*16;
    const int gR   = row0 + r;            // this lane's X-row
    const int b    = gR / NT_;            // -> (b,n,tt), once per lane
    const int rm   = gR - b*NT_;
    const int n    = rm / T_;
    const int tt   = rm - n*T_;
    uint32_t* dstrow = packed + (size_t)n*EPN_ + b*(T_*D_) + tt*D_;

    f32x4 acc[8];
    #pragma unroll
    for (int tile = 0; tile < 8; ++tile) acc[tile] = (f32x4){0.f,0.f,0.f,0.f};

    #pragma unroll
    for (int s = 0; s < 2; ++s) {
        const float* xp = X + (size_t)gR*64 + s*32 + q*8;
        const float4 x0 = *(const float4*)xp;
        const float4 x1 = *(const float4*)(xp + 4);
        short8v af;
        af[0] = (short)f32_to_bf16_bits(x0.x);
        af[1] = (short)f32_to_bf16_bits(x0.y);
        af[2] = (short)f32_to_bf16_bits(x0.z);
        af[3] = (short)f32_to_bf16_bits(x0.w);
        af[4] = (short)f32_to_bf16_bits(x1.x);
        af[5] = (short)f32_to_bf16_bits(x1.y);
        af[6] = (short)f32_to_bf16_bits(x1.z);
        af[7] = (short)f32_to_bf16_bits(x1.w);
        #pragma unroll
        for (int tile = 0; tile < 8; ++tile)
            acc[tile] = __builtin_amdgcn_mfma_f32_16x16x32_bf16(
                            wfrag[tile][s], af, acc[tile], 0, 0, 0);
    }

    // Epilogue: lane owns X-row gR, W-cols tile*16 + q*4 + reg.
    // Tile pair (tf, tf+4) = (feats cols, matching logit cols).
    #pragma unroll
    for (int tf = 0; tf < 4; ++tf) {
        const int d0 = tf*16 + q*4;
        const float4 bm4 = *(const float4*)&bm[d0];
        const float4 bp4 = *(const float4*)&bpp[d0];
        uint4 u;
        u.x = pack2(__builtin_amdgcn_exp2f(acc[tf+4][0] + bp4.x), acc[tf][0] + bm4.x);
        u.y = pack2(__builtin_amdgcn_exp2f(acc[tf+4][1] + bp4.y), acc[tf][1] + bm4.y);
        u.z = pack2(__builtin_amdgcn_exp2f(acc[tf+4][2] + bp4.z), acc[tf][2] + bm4.z);
        u.w = pack2(__builtin_amdgcn_exp2f(acc[tf+4][3] + bp4.w), acc[tf][3] + bm4.w);
        *(uint4*)(dstrow + d0) = u;
    }
}

// ---------- Kernel 2: per-node 8-edge softmax aggregation, K graphs ----------
// 1D grid of 12000 blocks (2 waves = 2 nodes each), XCD-phase partitioned
// (xcd = wgid%8 round-robin -> each XCD owns a contiguous 1.5-phase span, its
// L2 holds 1-2 packed byte-stripes for the whole kernel; validated R10: -11 µs).
__launch_bounds__(128, 4)
__global__ void gcn_kernel(const uint32_t* __restrict__ packed,
                           const float* __restrict__ input,
                           const int* __restrict__ edges,
                           const float* __restrict__ weight,
                           float* __restrict__ out) {
    const uint32_t wgid = blockIdx.x;          // [0,12000)
    const uint32_t xcd  = wgid & 7;            // assumed XCD id (round-robin)
    const uint32_t slot = wgid >> 3;           // [0,1500) within XCD
    const uint32_t vw   = xcd * 1500u + slot;  // phase-major virtual work item
    const int ss   = (int)(vw / 1000u);        // phase [0,12)
    const int pair = (int)(vw - (uint32_t)ss * 1000u);   // [0,1000)

    const int wv = __builtin_amdgcn_readfirstlane(threadIdx.x >> 6);  // wave 0/1
    const int n  = pair*2 + wv;
    const int t  = threadIdx.x & 63;      // lane

    const int vv = ss*64 + t;             // uint4 index within node row [0,768)
    const int b  = vv / V4PB_;
    const int r4 = vv - b*V4PB_;
    const size_t off4 = (size_t)b*(NT_*D_/4) + (size_t)n*V4PB_ + r4;
    const float4 inv = ((const float4*)input)[off4];   // residual, issued early

    // Wave-uniform edge indices (SGPR) for all 3 graphs.
    int srcs[24];
    #pragma unroll
    for (int k = 0; k < K_; ++k) {
        const int4 e0 = *(const int4*)(edges + (size_t)k*(2*E_) + n*DEG_);
        const int4 e1 = *(const int4*)(edges + (size_t)k*(2*E_) + n*DEG_ + 4);
        srcs[k*8+0]=e0.x; srcs[k*8+1]=e0.y; srcs[k*8+2]=e0.z; srcs[k*8+3]=e0.w;
        srcs[k*8+4]=e1.x; srcs[k*8+5]=e1.y; srcs[k*8+6]=e1.z; srcs[k*8+7]=e1.w;
    }

    uint4 pu[24];
    #pragma unroll
    for (int idx = 0; idx < 24; ++idx) {
        const char* base = (const char*)packed
                         + (size_t)((uint32_t)srcs[idx] * (uint32_t)ROWBYTES_);
        pu[idx] = *(const uint4*)(base + (size_t)vv * 16);
    }

    float acc[4] = {0.f, 0.f, 0.f, 0.f};
    #pragma unroll
    for (int k = 0; k < K_; ++k) {
        const float wk = weight[k];
        const uint32_t* pw = (const uint32_t*)&pu[k*8];
        #pragma unroll
        for (int qq = 0; qq < 4; ++qq) {
            float s = 0.f, num = 0.f;
            #pragma unroll
            for (int j = 0; j < 8; ++j) {
                const uint32_t u = pw[j*4 + qq];
                const float p = __uint_as_float(u & 0xFFFF0000u);  // exp(logit), bf16
                const float f = __uint_as_float(u << 16);          // feats, bf16
                s += p;
                num = fmaf(p, f, num);
            }
            acc[qq] += wk * num * __builtin_amdgcn_rcpf(s);
        }
    }

    float4 o;
    o.x = (acc[0] > 0.f ? acc[0] : 0.01f*acc[0]) + inv.x;
    o.y = (acc[1] > 0.f ? acc[1] : 0.01f*acc[1]) + inv.y;
    o.z = (acc[2] > 0.f ? acc[2] : 0.01f*acc[2]) + inv.z;
    o.w = (acc[3] > 0.f ? acc[3] : 0.01f*acc[3]) + inv.w;
    ((float4*)out)[off4] = o;
}

extern "C" void kernel_launch(void* const* d_in, const int* in_sizes, int n_in,
                              void* d_out, int out_size, void* d_ws, size_t ws_size,
                              hipStream_t stream) {
    const float* input  = (const float*)d_in[0];
    const float* Wm     = (const float*)d_in[1];
    const float* bm     = (const float*)d_in[2];
    const float* Wa     = (const float*)d_in[3];
    // d_in[4] = b_attn (cancels inside per-dst softmax), unused
    const float* weight = (const float*)d_in[5];
    const int*   edges  = (const int*)d_in[6];
    float* out = (float*)d_out;
    uint32_t* packed = (uint32_t*)d_ws;   // [N][B][T][D] of (bf16 exp(logit) | bf16 feats)

    // Prep scratch lives in the head of d_out; gcn_kernel fully overwrites out.
    uint16_t* WBf = (uint16_t*)d_out;             // 16 fragment-slots x 64 lanes x 16 B = 16 KB
    float*    bpp = (float*)d_out + 4096;         // 64 floats

    hipLaunchKernelGGL(prep_kernel, dim3(17), dim3(64), 0, stream, Wm, Wa, bm, WBf, bpp);
    hipLaunchKernelGGL(mlp_mfma, dim3(ROWS_/64), dim3(256), 0, stream,
                       input, WBf, bm, bpp, packed);
    hipLaunchKernelGGL(gcn_kernel, dim3(12000), dim3(128), 0, stream,
                       packed, input, edges, weight, out);
}

// Round 13
// 50.150 us; speedup vs baseline: 1.1058x; 1.0190x over previous
//
#include <hip/hip_runtime.h>
#include <hip/hip_bf16.h>
#include <stdint.h>

#define B_ 4
#define N_ 2000
#define T_ 12
#define D_ 64
#define K_ 3
#define DEG_ 8
#define E_ (N_*DEG_)              // 16000
#define ROWS_ (B_*N_*T_)          // 96000
#define NT_ (N_*T_)               // 24000
#define EPN_ (B_*T_*D_)           // 3072 elements per node row
#define V4PB_ (T_*D_/4)           // 192 vec4 per (node,b)
#define ROWBYTES_ (EPN_*4)        // 12288 bytes per node row
#define LOG2E_ 1.4426950408889634f

typedef __attribute__((ext_vector_type(8))) short short8v;   // 8 bf16 = 4 VGPR
typedef __attribute__((ext_vector_type(4))) float f32x4;     // MFMA acc

__device__ __forceinline__ uint32_t f32_to_bf16_bits(float x) {
    uint32_t u = __float_as_uint(x);
    return (u + 0x7FFFu + ((u >> 16) & 1u)) >> 16;   // RNE
}
__device__ __forceinline__ uint32_t pack2(float p, float f) {
    return (f32_to_bf16_bits(p) << 16) | f32_to_bf16_bits(f);
}
__device__ __forceinline__ short8v cvt8(float4 lo, float4 hi) {
    short8v af;
    af[0] = (short)f32_to_bf16_bits(lo.x);
    af[1] = (short)f32_to_bf16_bits(lo.y);
    af[2] = (short)f32_to_bf16_bits(lo.z);
    af[3] = (short)f32_to_bf16_bits(lo.w);
    af[4] = (short)f32_to_bf16_bits(hi.x);
    af[5] = (short)f32_to_bf16_bits(hi.y);
    af[6] = (short)f32_to_bf16_bits(hi.z);
    af[7] = (short)f32_to_bf16_bits(hi.w);
    return af;
}

// ---------- Kernel 0 (prep): fragment-linear W table + bias ----------
// WBf[(tile*2+s)*64 + lane][e] = bf16 of W-col c = tile*16 + (lane&15),
// k = s*32 + (lane>>4)*8 + e; c<64 -> Wm[:,c], c>=64 -> log2e*(Wm@W1)[:,c-64]
// (W1 = W_attn[:64]; W2/b_attn cancel in the per-dst softmax; max-shift cancels
// so the logit half is pre-exponentiated downstream).
__global__ void prep_kernel(const float* __restrict__ Wm,
                            const float* __restrict__ Wa,
                            const float* __restrict__ bm,
                            uint16_t* __restrict__ WBf,
                            float* __restrict__ bpp) {
    const int blk  = blockIdx.x;          // 0..16
    const int lane = threadIdx.x;         // 64
    if (blk < 16) {
        const int tile = blk >> 1, s = blk & 1;
        const int r = lane & 15, q = lane >> 4;
        const int c = tile*16 + r;
        uint16_t o[8];
        #pragma unroll
        for (int e = 0; e < 8; ++e) {
            const int k = s*32 + q*8 + e;
            float v;
            if (c < 64) {
                v = Wm[k*64 + c];
            } else {
                v = 0.f;
                #pragma unroll
                for (int j = 0; j < 64; ++j) v += Wm[k*64 + j] * Wa[j*64 + (c - 64)];
                v *= LOG2E_;
            }
            o[e] = (uint16_t)f32_to_bf16_bits(v);
        }
        *(uint4*)(WBf + (size_t)(blk*64 + lane)*8) = *(const uint4*)o;
    } else {
        float s = 0.f;
        #pragma unroll
        for (int e = 0; e < 64; ++e) s += bm[e] * Wa[e*64 + lane];
        bpp[lane] = s * LOG2E_;
    }
}

// ---------- Kernel 1: MFMA GEMM [96000x64]@[64x128] -> pack (exp2(logit), feat) ----------
// Fat-wave v3: block = 128 rows, 4 waves; wave = 32 rows (two 16-row A-tiles
// sharing one wfrag set) x 128 cols = 32 MFMA. All 8 X row-tile loads issue
// before any compute (single exposed X-latency); wfrag loads amortize over 2x
// MFMA vs R12. Swapped operands (validated): acc = mfma(wfrag, af) -> lane owns
// one X-row x 4 consecutive W-cols -> d-contiguous uint4 stores.
__launch_bounds__(256)
__global__ void mlp_mfma(const float* __restrict__ X,
                         const uint16_t* __restrict__ WBf,
                         const float* __restrict__ bm,
                         const float* __restrict__ bpp,
                         uint32_t* __restrict__ packed) {
    const int t    = threadIdx.x;
    const int wave = t >> 6, lane = t & 63;
    const int r    = lane & 15, q = lane >> 4;

    const int row0 = blockIdx.x*128 + wave*32;
    const int gR0  = row0 + r;            // row-tile 0
    const int gR1  = row0 + 16 + r;       // row-tile 1

    // X loads first (long latency), both row-tiles, both K-halves.
    const float* xp0 = X + (size_t)gR0*64 + q*8;
    const float* xp1 = X + (size_t)gR1*64 + q*8;
    const float4 a00 = *(const float4*)(xp0);
    const float4 a01 = *(const float4*)(xp0 + 4);
    const float4 a02 = *(const float4*)(xp0 + 32);
    const float4 a03 = *(const float4*)(xp0 + 36);
    const float4 a10 = *(const float4*)(xp1);
    const float4 a11 = *(const float4*)(xp1 + 4);
    const float4 a12 = *(const float4*)(xp1 + 32);
    const float4 a13 = *(const float4*)(xp1 + 36);

    // W fragments, fragment-linear: 16 contiguous 1-KB wave loads (L1-resident).
    short8v wfrag[8][2];
    #pragma unroll
    for (int tile = 0; tile < 8; ++tile)
        #pragma unroll
        for (int s = 0; s < 2; ++s)
            wfrag[tile][s] = *(const short8v*)(WBf + (size_t)((tile*2+s)*64 + lane)*8);

    f32x4 acc0[8], acc1[8];
    #pragma unroll
    for (int tile = 0; tile < 8; ++tile) {
        acc0[tile] = (f32x4){0.f,0.f,0.f,0.f};
        acc1[tile] = (f32x4){0.f,0.f,0.f,0.f};
    }

    {
        const short8v af = cvt8(a00, a01);           // rt0, k 0..31
        #pragma unroll
        for (int tile = 0; tile < 8; ++tile)
            acc0[tile] = __builtin_amdgcn_mfma_f32_16x16x32_bf16(wfrag[tile][0], af, acc0[tile], 0, 0, 0);
    }
    {
        const short8v af = cvt8(a02, a03);           // rt0, k 32..63
        #pragma unroll
        for (int tile = 0; tile < 8; ++tile)
            acc0[tile] = __builtin_amdgcn_mfma_f32_16x16x32_bf16(wfrag[tile][1], af, acc0[tile], 0, 0, 0);
    }
    {
        const short8v af = cvt8(a10, a11);           // rt1, k 0..31
        #pragma unroll
        for (int tile = 0; tile < 8; ++tile)
            acc1[tile] = __builtin_amdgcn_mfma_f32_16x16x32_bf16(wfrag[tile][0], af, acc1[tile], 0, 0, 0);
    }
    {
        const short8v af = cvt8(a12, a13);           // rt1, k 32..63
        #pragma unroll
        for (int tile = 0; tile < 8; ++tile)
            acc1[tile] = __builtin_amdgcn_mfma_f32_16x16x32_bf16(wfrag[tile][1], af, acc1[tile], 0, 0, 0);
    }

    // Epilogue per row-tile: lane owns X-row gR, W-cols tile*16 + q*4 + reg.
    // Tile pair (tf, tf+4) = (feats cols, matching logit cols).
    #pragma unroll
    for (int rt = 0; rt < 2; ++rt) {
        const int gR = rt ? gR1 : gR0;
        const f32x4* acc = rt ? acc1 : acc0;
        const int b  = gR / NT_;
        const int rm = gR - b*NT_;
        const int n  = rm / T_;
        const int tt = rm - n*T_;
        uint32_t* dstrow = packed + (size_t)n*EPN_ + b*(T_*D_) + tt*D_;
        #pragma unroll
        for (int tf = 0; tf < 4; ++tf) {
            const int d0 = tf*16 + q*4;
            const float4 bm4 = *(const float4*)&bm[d0];
            const float4 bp4 = *(const float4*)&bpp[d0];
            uint4 u;
            u.x = pack2(__builtin_amdgcn_exp2f(acc[tf+4][0] + bp4.x), acc[tf][0] + bm4.x);
            u.y = pack2(__builtin_amdgcn_exp2f(acc[tf+4][1] + bp4.y), acc[tf][1] + bm4.y);
            u.z = pack2(__builtin_amdgcn_exp2f(acc[tf+4][2] + bp4.z), acc[tf][2] + bm4.z);
            u.w = pack2(__builtin_amdgcn_exp2f(acc[tf+4][3] + bp4.w), acc[tf][3] + bm4.w);
            *(uint4*)(dstrow + d0) = u;
        }
    }
}

// ---------- Kernel 2: per-node 8-edge softmax aggregation, K graphs ----------
// 1D grid of 12000 blocks (2 waves = 2 nodes each), XCD-phase partitioned
// (xcd = wgid%8 round-robin -> each XCD owns a contiguous 1.5-phase span, its
// L2 holds 1-2 packed byte-stripes for the whole kernel; validated R10: -11 µs).
__launch_bounds__(128, 4)
__global__ void gcn_kernel(const uint32_t* __restrict__ packed,
                           const float* __restrict__ input,
                           const int* __restrict__ edges,
                           const float* __restrict__ weight,
                           float* __restrict__ out) {
    const uint32_t wgid = blockIdx.x;          // [0,12000)
    const uint32_t xcd  = wgid & 7;            // assumed XCD id (round-robin)
    const uint32_t slot = wgid >> 3;           // [0,1500) within XCD
    const uint32_t vw   = xcd * 1500u + slot;  // phase-major virtual work item
    const int ss   = (int)(vw / 1000u);        // phase [0,12)
    const int pair = (int)(vw - (uint32_t)ss * 1000u);   // [0,1000)

    const int wv = __builtin_amdgcn_readfirstlane(threadIdx.x >> 6);  // wave 0/1
    const int n  = pair*2 + wv;
    const int t  = threadIdx.x & 63;      // lane

    const int vv = ss*64 + t;             // uint4 index within node row [0,768)
    const int b  = vv / V4PB_;
    const int r4 = vv - b*V4PB_;
    const size_t off4 = (size_t)b*(NT_*D_/4) + (size_t)n*V4PB_ + r4;
    const float4 inv = ((const float4*)input)[off4];   // residual, issued early

    // Wave-uniform edge indices (SGPR) for all 3 graphs.
    int srcs[24];
    #pragma unroll
    for (int k = 0; k < K_; ++k) {
        const int4 e0 = *(const int4*)(edges + (size_t)k*(2*E_) + n*DEG_);
        const int4 e1 = *(const int4*)(edges + (size_t)k*(2*E_) + n*DEG_ + 4);
        srcs[k*8+0]=e0.x; srcs[k*8+1]=e0.y; srcs[k*8+2]=e0.z; srcs[k*8+3]=e0.w;
        srcs[k*8+4]=e1.x; srcs[k*8+5]=e1.y; srcs[k*8+6]=e1.z; srcs[k*8+7]=e1.w;
    }

    uint4 pu[24];
    #pragma unroll
    for (int idx = 0; idx < 24; ++idx) {
        const char* base = (const char*)packed
                         + (size_t)((uint32_t)srcs[idx] * (uint32_t)ROWBYTES_);
        pu[idx] = *(const uint4*)(base + (size_t)vv * 16);
    }

    float acc[4] = {0.f, 0.f, 0.f, 0.f};
    #pragma unroll
    for (int k = 0; k < K_; ++k) {
        const float wk = weight[k];
        const uint32_t* pw = (const uint32_t*)&pu[k*8];
        #pragma unroll
        for (int qq = 0; qq < 4; ++qq) {
            float s = 0.f, num = 0.f;
            #pragma unroll
            for (int j = 0; j < 8; ++j) {
                const uint32_t u = pw[j*4 + qq];
                const float p = __uint_as_float(u & 0xFFFF0000u);  // exp(logit), bf16
                const float f = __uint_as_float(u << 16);          // feats, bf16
                s += p;
                num = fmaf(p, f, num);
            }
            acc[qq] += wk * num * __builtin_amdgcn_rcpf(s);
        }
    }

    float4 o;
    o.x = (acc[0] > 0.f ? acc[0] : 0.01f*acc[0]) + inv.x;
    o.y = (acc[1] > 0.f ? acc[1] : 0.01f*acc[1]) + inv.y;
    o.z = (acc[2] > 0.f ? acc[2] : 0.01f*acc[2]) + inv.z;
    o.w = (acc[3] > 0.f ? acc[3] : 0.01f*acc[3]) + inv.w;
    ((float4*)out)[off4] = o;
}

extern "C" void kernel_launch(void* const* d_in, const int* in_sizes, int n_in,
                              void* d_out, int out_size, void* d_ws, size_t ws_size,
                              hipStream_t stream) {
    const float* input  = (const float*)d_in[0];
    const float* Wm     = (const float*)d_in[1];
    const float* bm     = (const float*)d_in[2];
    const float* Wa     = (const float*)d_in[3];
    // d_in[4] = b_attn (cancels inside per-dst softmax), unused
    const float* weight = (const float*)d_in[5];
    const int*   edges  = (const int*)d_in[6];
    float* out = (float*)d_out;
    uint32_t* packed = (uint32_t*)d_ws;   // [N][B][T][D] of (bf16 exp(logit) | bf16 feats)

    // Prep scratch lives in the head of d_out; gcn_kernel fully overwrites out.
    uint16_t* WBf = (uint16_t*)d_out;             // 16 fragment-slots x 64 lanes x 16 B = 16 KB
    float*    bpp = (float*)d_out + 4096;         // 64 floats

    hipLaunchKernelGGL(prep_kernel, dim3(17), dim3(64), 0, stream, Wm, Wa, bm, WBf, bpp);
    hipLaunchKernelGGL(mlp_mfma, dim3(ROWS_/128), dim3(256), 0, stream,
                       input, WBf, bm, bpp, packed);
    hipLaunchKernelGGL(gcn_kernel, dim3(12000), dim3(128), 0, stream,
                       packed, input, edges, weight, out);
}